// Round 3
// baseline (155.854 us; speedup 1.0000x reference)
//
#include <hip/hip_runtime.h>
#include <math.h>

// CliffordDDIDecoder — R15: proj K-loop rewritten as a continuous 16-chunk
// (32-k) stream with ZERO vmcnt(0) drains (R12/R14 diagnosis: proj time ==
// 40MB / 944 GB/s; h-loading was latency-bound because every chunk's
// wb0=wb1 copy forced a FIFO vmcnt drain and every quarter's __syncthreads
// drained again — in-flight loads never accumulated).
//  * h: 4-deep register pipeline (issue chunk g+4 at body g, convert at
//    body g+3; ~2 bodies of latency coverage), unrolled x4 -> static regs.
//  * W: parity-staged wbA/wbB, NO copy -> MFMA waits are counted vmcnt,
//    younger h loads stay in flight (FIFO-safe issue order per body:
//    convert-h (oldest) -> W loads -> MFMA -> issue-h (newest)).
//  * barriers: raw s_barrier + lgkmcnt(0) only (T3/T4); hs quadruple-
//    buffered 4KB bufs (write@X-1 vs read@X-4 separated by >=2 barriers).
// Accumulation order/chunk order/RNE staging identical to R14 -> bit-
// identical outputs. LN/GEMM2 unchanged (xs pad back to 264; LDS 51 KB).
// prep/cliff R7-verbatim. MFMA readout BANNED.

#define B_ 16384
#define D_ 512
#define H_ 256
#define R_ 95

typedef __attribute__((ext_vector_type(8))) short short8;   // 8 bf16
typedef __attribute__((ext_vector_type(4))) float f32x4;

#define MFMA(a, b, c) __builtin_amdgcn_mfma_f32_16x16x32_bf16(a, b, c, 0, 0, 0)

__device__ __forceinline__ short f2bf(float x) {            // fp32 -> bf16 RNE
    union { float f; unsigned u; } v; v.f = x;
    unsigned r = v.u + 0x7fffu + ((v.u >> 16) & 1u);
    return (short)(r >> 16);
}
__device__ __forceinline__ float bf2f(short s) {
    union { float f; unsigned u; } v;
    v.u = ((unsigned)(unsigned short)s) << 16;
    return v.f;
}

// exact GELU, erf via Abramowitz-Stegun 7.1.26 (max abs err 1.5e-7)
__device__ __forceinline__ float gelu_fast(float x) {
    const float z  = x * 0.70710678118654752f;
    const float az = fabsf(z);
    const float t  = 1.0f / fmaf(0.3275911f, az, 1.0f);
    float p = fmaf(1.061405429f, t, -1.453152027f);
    p = fmaf(p, t, 1.421413741f);
    p = fmaf(p, t, -0.284496736f);
    p = fmaf(p, t, 0.254829592f);
    p *= t;
    const float e  = 1.0f - p * __expf(-az * az);
    const float er = copysignf(e, z);
    return 0.5f * x * (1.0f + er);
}

// ---- prep: W1 -> [16 chunk][256 n][32 k] bf16 ; W2 -> [64 n][256 k] bf16 ----
__global__ __launch_bounds__(256)
void cdd_prep_kernel(const float* __restrict__ Wp1, const float* __restrict__ Wv1,
                     const float* __restrict__ Wp2, const float* __restrict__ Wv2,
                     short* __restrict__ W1c_p, short* __restrict__ W1c_v,
                     short* __restrict__ W2t_p, short* __restrict__ W2t_v)
{
    const int o = blockIdx.x * 256 + threadIdx.x;
    if (o < 16 * 256 * 32) {            // n-fast: coalesced W1 reads
        const int n = o & 255, kin = (o >> 8) & 31, ch = o >> 13;
        const int src = (ch * 32 + kin) * 256 + n;
        const int dst = ch * 8192 + n * 32 + kin;
        W1c_p[dst] = f2bf(Wp1[src]);
        W1c_v[dst] = f2bf(Wv1[src]);
    }
    if (o < 64 * 256) {
        const int n = o >> 8, k = o & 255;
        W2t_p[o] = f2bf(Wp2[k * 64 + n]);
        W2t_v[o] = f2bf(Wv2[k * 64 + n]);
    }
}

// one streamed body: convert chunk g+1 -> LDS, barrier, load W(g+1),
// MFMA chunk g, issue h(g+4). All stage/buf indices compile-time.
#define PROJ_BODY(Kk, BUF_C, BUF_R, S_I0, S_I1, S_C0, S_C1, WB_USE, WB_LD)  \
  do {                                                                      \
    const int g = gb + (Kk);                                                \
    if (g <= 14) {                     /* 1. convert chunk g+1 -> LDS */    \
      short8 pk;                                                            \
      pk[0]=f2bf(S_C0.x); pk[1]=f2bf(S_C0.y); pk[2]=f2bf(S_C0.z); pk[3]=f2bf(S_C0.w); \
      pk[4]=f2bf(S_C1.x); pk[5]=f2bf(S_C1.y); pk[6]=f2bf(S_C1.z); pk[7]=f2bf(S_C1.w); \
      *(short8*)(hs + (BUF_C) * 2048 + wdst) = pk;                          \
    }                                                                       \
    asm volatile("s_waitcnt lgkmcnt(0)" ::: "memory");  /* 2. raw barrier */\
    __builtin_amdgcn_s_barrier();                                           \
    asm volatile("" ::: "memory");                                          \
    if (g <= 14) {                     /* 3. W loads for chunk g+1 */       \
      _Pragma("unroll")                                                     \
      for (int nt = 0; nt < 4; ++nt)                                        \
        WB_LD[nt] = *(const short8*)(Wb0 + (g + 1) * 8192 + nt * 512);      \
    }                                                                       \
    {                                  /* 4. MFMA chunk g */                \
      const short8 a0 = *(const short8*)(hs + (BUF_R) * 2048 + (0 * 64 + l) * 8); \
      const short8 a1 = *(const short8*)(hs + (BUF_R) * 2048 + (1 * 64 + l) * 8); \
      const short8 a2 = *(const short8*)(hs + (BUF_R) * 2048 + (2 * 64 + l) * 8); \
      const short8 a3 = *(const short8*)(hs + (BUF_R) * 2048 + (3 * 64 + l) * 8); \
      _Pragma("unroll")                                                     \
      for (int nt = 0; nt < 4; ++nt) {                                      \
        acc1[0][nt] = MFMA(a0, WB_USE[nt], acc1[0][nt]);                    \
        acc1[1][nt] = MFMA(a1, WB_USE[nt], acc1[1][nt]);                    \
        acc1[2][nt] = MFMA(a2, WB_USE[nt], acc1[2][nt]);                    \
        acc1[3][nt] = MFMA(a3, WB_USE[nt], acc1[3][nt]);                    \
      }                                                                     \
    }                                                                       \
    asm volatile("" ::: "memory");     /* pin issue point below MFMAs */    \
    if (g <= 11) {                     /* 5. issue h chunk g+4 (newest) */  \
      S_I0 = *(const float4*)(hbase + (g + 4) * 32);                        \
      S_I1 = *(const float4*)(hbase + (g + 4) * 32 + 4);                    \
    }                                                                       \
  } while (0)

// ---- proj: x1=h@W1+b1 -> LN -> exact GELU -> m=x@W2+b2 (bf16 to ws) --------
// 64-row blocks, 256 thr (4 waves); wave w owns cols [64w,64w+64), mt 0..3.
__global__ __launch_bounds__(256, 2)
void cdd_proj_kernel(const float* __restrict__ h_p, const float* __restrict__ h_v,
                     const float* __restrict__ bp1, const float* __restrict__ lgp,
                     const float* __restrict__ lbp, const float* __restrict__ bp2,
                     const float* __restrict__ bv1, const float* __restrict__ lgv,
                     const float* __restrict__ lbv, const float* __restrict__ bv2,
                     const short* __restrict__ W1c_p, const short* __restrict__ W1c_v,
                     const short* __restrict__ W2t_p, const short* __restrict__ W2t_v,
                     short* __restrict__ mp_out, short* __restrict__ mv_out)
{
    // hs: 4 chunk-buffers x (64 rows x 32 k) bf16, fragment-major:
    // lane l's 8 bf16 for mt-block at (mt*64 + l)*8 -> ds ops conflict-free.
    __shared__ __align__(16) short hs[4 * 2048];    // 16 KB
    __shared__ __align__(16) short xs[64 * 264];    // 33 KB
    __shared__ __align__(16) float lnbuf[512];      // 2 KB   (total 51 KB)

    const int which = blockIdx.y;
    const float* __restrict__ h   = which ? h_v : h_p;
    const float* __restrict__ b1  = which ? bv1 : bp1;
    const float* __restrict__ lg  = which ? lgv : lgp;
    const float* __restrict__ lb  = which ? lbv : lbp;
    const float* __restrict__ b2  = which ? bv2 : bp2;
    const short* __restrict__ W1c = which ? W1c_v : W1c_p;
    const short* __restrict__ W2t = which ? W2t_v : W2t_p;
    short* __restrict__ mo = which ? mv_out : mp_out;

    const int t = threadIdx.x;
    const int w = t >> 6, l = t & 63, q = l >> 4, c = l & 15;
    const int b0 = blockIdx.x * 64;
    // staging map: 4 threads/row; the 4 lanes of a row cover 32 consecutive k.
    const int srow = t >> 2, kq4 = (t & 3);
    const int mt_s = srow >> 4, c_s = srow & 15;
    const int wdst = (mt_s * 64 + kq4 * 16 + c_s) * 8;   // shorts, within buf

    f32x4 acc1[4][4];
#pragma unroll
    for (int mt = 0; mt < 4; ++mt)
#pragma unroll
        for (int nt = 0; nt < 4; ++nt) acc1[mt][nt] = 0;

    const short* Wb0 = W1c + (w * 64 + c) * 32 + q * 8;
    const float* hbase = h + (size_t)(b0 + srow) * D_ + kq4 * 8;

    // ---- prologue: issue chunks 0..3, W chunk 0, convert chunk 0 ----------
    float4 s0a = *(const float4*)(hbase + 0 * 32), s0b = *(const float4*)(hbase + 0 * 32 + 4);
    float4 s1a = *(const float4*)(hbase + 1 * 32), s1b = *(const float4*)(hbase + 1 * 32 + 4);
    float4 s2a = *(const float4*)(hbase + 2 * 32), s2b = *(const float4*)(hbase + 2 * 32 + 4);
    float4 s3a = *(const float4*)(hbase + 3 * 32), s3b = *(const float4*)(hbase + 3 * 32 + 4);
    short8 wbA[4], wbB[4];
#pragma unroll
    for (int nt = 0; nt < 4; ++nt) wbA[nt] = *(const short8*)(Wb0 + nt * 512);
    {
        short8 pk;
        pk[0]=f2bf(s0a.x); pk[1]=f2bf(s0a.y); pk[2]=f2bf(s0a.z); pk[3]=f2bf(s0a.w);
        pk[4]=f2bf(s0b.x); pk[5]=f2bf(s0b.y); pk[6]=f2bf(s0b.z); pk[7]=f2bf(s0b.w);
        *(short8*)(hs + 0 * 2048 + wdst) = pk;
    }

    // ---- 16 streamed bodies, unrolled x4 (all indices compile-time) -------
    for (int gb = 0; gb < 16; gb += 4) {
        PROJ_BODY(0, 1, 0, s0a, s0b, s1a, s1b, wbA, wbB);
        PROJ_BODY(1, 2, 1, s1a, s1b, s2a, s2b, wbB, wbA);
        PROJ_BODY(2, 3, 2, s2a, s2b, s3a, s3b, wbA, wbB);
        PROJ_BODY(3, 0, 3, s3a, s3b, s0a, s0b, wbB, wbA);
    }

    // ---------------- bias + LayerNorm (fp32 stats) + fast exact GELU ------
    float bb[4], gg[4], ee[4];
#pragma unroll
    for (int nt = 0; nt < 4; ++nt) {
        const int col = w * 64 + nt * 16 + c;
        bb[nt] = b1[col]; gg[nt] = lg[col]; ee[nt] = lb[col];
    }
#pragma unroll
    for (int mt = 0; mt < 4; ++mt)
#pragma unroll
        for (int reg = 0; reg < 4; ++reg) {
            float s1 = 0.f, s2 = 0.f;
#pragma unroll
            for (int nt = 0; nt < 4; ++nt) {
                const float a = acc1[mt][nt][reg] + bb[nt];
                acc1[mt][nt][reg] = a;
                s1 += a; s2 += a * a;
            }
#pragma unroll
            for (int m = 1; m <= 8; m <<= 1) {   // reduce over c (16 lanes)
                s1 += __shfl_xor(s1, m, 64);
                s2 += __shfl_xor(s2, m, 64);
            }
            if (c == 0) {
                const int row = mt * 16 + q * 4 + reg;
                *(float2*)(lnbuf + (w * 64 + row) * 2) = make_float2(s1, s2);
            }
        }
    __syncthreads();
#pragma unroll
    for (int mt = 0; mt < 4; ++mt)
#pragma unroll
        for (int reg = 0; reg < 4; ++reg) {
            const int row = mt * 16 + q * 4 + reg;
            float S1 = 0.f, S2 = 0.f;
#pragma unroll
            for (int w2 = 0; w2 < 4; ++w2) {
                const float2 p = *(const float2*)(lnbuf + (w2 * 64 + row) * 2);
                S1 += p.x; S2 += p.y;
            }
            const float mu  = S1 * (1.f / 256.f);
            const float var = S2 * (1.f / 256.f) - mu * mu;
            const float rs  = rsqrtf(var + 1e-5f);
#pragma unroll
            for (int nt = 0; nt < 4; ++nt) {
                const int col = w * 64 + nt * 16 + c;
                const float xv = (acc1[mt][nt][reg] - mu) * rs * gg[nt] + ee[nt];
                xs[row * 264 + col] = f2bf(gelu_fast(xv));
            }
        }
    __syncthreads();

    // ---------------- GEMM2: m(64x64) = xs(64x256) @ W2(256x64) + b2 -------
    // wave w owns n-cols [16w,16w+16); mt 0..3 (R7-proven pattern).
    f32x4 acc2[4];
#pragma unroll
    for (int mt = 0; mt < 4; ++mt) acc2[mt] = 0;
    const short* W2b = W2t + (w * 16 + c) * 256 + q * 8;
#pragma unroll
    for (int ks = 0; ks < 8; ++ks) {
        const short8 wbk = *(const short8*)(W2b + ks * 32);
#pragma unroll
        for (int mt = 0; mt < 4; ++mt) {
            const short8 xa = *(const short8*)(xs + (mt * 16 + c) * 264 + ks * 32 + q * 8);
            acc2[mt] = MFMA(xa, wbk, acc2[mt]);
        }
    }
    const float bc = b2[w * 16 + c];
#pragma unroll
    for (int mt = 0; mt < 4; ++mt)
#pragma unroll
        for (int reg = 0; reg < 4; ++reg) {
            const int row = mt * 16 + q * 4 + reg;
            mo[(size_t)(b0 + row) * 64 + w * 16 + c] = f2bf(acc2[mt][reg] + bc);
        }
}

// ---- cliff: R7-verbatim — Clifford collapse + VALU-dot readout, T in LDS ---
__global__ __launch_bounds__(256, 2)
void cdd_cliff_kernel(const short* __restrict__ mp, const short* __restrict__ mv,
                      const float* __restrict__ T, const float* __restrict__ gw,
                      float* __restrict__ out)
{
    __shared__ __align__(16) float wfl[32 * 68];    // collapsed w, fp32
    __shared__ __align__(16) float ts[95 * 68];     // T staged (pad 68)
    const int t  = threadIdx.x;
    const int b0 = blockIdx.x * 32;

    // stage T: 95 rows x 16 float4
#pragma unroll
    for (int k = 0; k < 6; ++k) {
        const int o = t + k * 256;
        if (o < 95 * 16) {
            const int rr = o >> 4, c4 = (o & 15) << 2;
            *(float4*)(ts + rr * 68 + c4) = *(const float4*)(T + rr * 64 + c4);
        }
    }

    // collapse: w[row][kq*8 .. +8] from mp,mv (fp32 math, bf16 inputs)
    {
        const int row = t >> 3, kq = t & 7;
        float g[8];
#pragma unroll
        for (int i = 0; i < 8; ++i) g[i] = gw[i];
        const short8 p8 = *(const short8*)(mp + (size_t)(b0 + row) * 64 + kq * 8);
        const short8 q8 = *(const short8*)(mv + (size_t)(b0 + row) * 64 + kq * 8);
        float mpv[8], mvv[8];
#pragma unroll
        for (int i = 0; i < 8; ++i) { mpv[i] = bf2f(p8[i]); mvv[i] = bf2f(q8[i]); }

        constexpr int MSK[8] = {0, 1, 2, 4, 3, 5, 6, 7};
        float v[8];
#pragma unroll
        for (int m = 0; m < 8; ++m) {
            float s = 0.f;
#pragma unroll
            for (int j = 0; j < 8; ++j) {
                const int am = MSK[m], bm = MSK[j];
                const int par = (__popc((am >> 1) & bm) + __popc((am >> 2) & bm)) & 1;
                const float sg = par ? -1.f : 1.f;
                s = fmaf(sg * g[MSK[am ^ bm]], mvv[j], s);
            }
            v[m] = s;
        }
#pragma unroll
        for (int l2 = 0; l2 < 8; ++l2) {
            float s = 0.f;
#pragma unroll
            for (int i = 0; i < 8; ++i) {
                const int am = MSK[i], bm = MSK[l2];
                const int par = (__popc((am >> 1) & bm) + __popc((am >> 2) & bm)) & 1;
                const float sg = par ? -1.f : 1.f;
                s = fmaf(sg * mpv[i], v[MSK[am ^ bm]], s);
            }
            wfl[row * 68 + kq * 8 + l2] = s;
        }
    }
    __syncthreads();

    // readout: thread group-of-8 owns one b-row; w row in registers;
    // ts reads: 8 distinct rows x 8-fold broadcast -> conflict-free.
    {
        const int rr = t >> 3, rl = t & 7;
        float4 wv[16];
#pragma unroll
        for (int cc = 0; cc < 16; ++cc)
            wv[cc] = *(const float4*)(wfl + rr * 68 + cc * 4);
#pragma unroll
        for (int k = 0; k < 12; ++k) {
            const int r = rl + (k << 3);
            if (r < R_) {
                float s = 0.f;
#pragma unroll
                for (int cc = 0; cc < 16; ++cc) {
                    const float4 tv = *(const float4*)(ts + r * 68 + cc * 4);
                    s += wv[cc].x * tv.x + wv[cc].y * tv.y
                       + wv[cc].z * tv.z + wv[cc].w * tv.w;
                }
                out[(size_t)(b0 + rr) * R_ + r] = 0.125f * s;
            }
        }
    }
}

extern "C" void kernel_launch(void* const* d_in, const int* in_sizes, int n_in,
                              void* d_out, int out_size, void* d_ws, size_t ws_size,
                              hipStream_t stream)
{
    const float* h_p = (const float*)d_in[0];
    const float* h_v = (const float*)d_in[1];
    const float* Wp1 = (const float*)d_in[2];
    const float* bp1 = (const float*)d_in[3];
    const float* lgp = (const float*)d_in[4];
    const float* lbp = (const float*)d_in[5];
    const float* Wp2 = (const float*)d_in[6];
    const float* bp2 = (const float*)d_in[7];
    const float* Wv1 = (const float*)d_in[8];
    const float* bv1 = (const float*)d_in[9];
    const float* lgv = (const float*)d_in[10];
    const float* lbv = (const float*)d_in[11];
    const float* Wv2 = (const float*)d_in[12];
    const float* bv2 = (const float*)d_in[13];
    const float* T   = (const float*)d_in[14];
    const float* gw  = (const float*)d_in[15];
    float* out = (float*)d_out;

    // ws layout (4.78 MB), R4/R7-verbatim:
    short* W1c_p = (short*)d_ws;                 // [16][256][32]
    short* W1c_v = W1c_p + 16 * 256 * 32;
    short* W2t_p = W1c_v + 16 * 256 * 32;        // [64][256]
    short* W2t_v = W2t_p + 64 * 256;
    short* mp    = W2t_v + 64 * 256;             // (B,64) bf16
    short* mv    = mp + (size_t)B_ * 64;         // (B,64) bf16

    cdd_prep_kernel<<<512, 256, 0, stream>>>(Wp1, Wv1, Wp2, Wv2,
                                             W1c_p, W1c_v, W2t_p, W2t_v);
    dim3 g1(B_ / 64, 2);
    cdd_proj_kernel<<<g1, 256, 0, stream>>>(h_p, h_v,
                                            bp1, lgp, lbp, bp2,
                                            bv1, lgv, lbv, bv2,
                                            W1c_p, W1c_v, W2t_p, W2t_v,
                                            mp, mv);
    cdd_cliff_kernel<<<B_ / 32, 256, 0, stream>>>(mp, mv, T, gw, out);
}